// Round 1
// baseline (425.681 us; speedup 1.0000x reference)
//
#include <hip/hip_runtime.h>
#include <hip/hip_bf16.h>
#include <math.h>

typedef float float4v __attribute__((ext_vector_type(4)));

#define BA 1024          // B*L
#define QD 512           // QUERY_DIM
#define CD 1576          // CTX_DIM
#define NV 36            // N_VIEWS
#define KVD 112
#define HLD 2200         // 1576 + 512 + 112
#define WKLD 2476        // W_key leading dim

// ---------------- pano affinity, closed form ----------------
__device__ __forceinline__ float pano_adj(int v, int w) {
    if (v == w) return 1.f;
    int rv = v / 12, rw = w / 12;
    int dr = rv - rw; if (dr < 0) dr = -dr;
    if (dr > 1) return 0.f;
    int dc = ((v % 12) - (w % 12) + 12) % 12;
    if (dc == 1 || dc == 11) return 1.f;
    if (dc == 0 && dr == 1) return 1.f;
    return 0.f;
}

__device__ __forceinline__ float pano_entry(int i, int j) {
    if (i == j) return 1.0f;
    float val;
    if (i >= 1 && i <= 34 && j >= 1 && j <= 34) {
        const float wgt0 = 0.25f, wgt1 = 0.5f, wgt2 = 0.25f;
        float wr[3] = {wgt0, wgt1, wgt2};
        val = 0.f;
        #pragma unroll
        for (int di = 0; di < 3; ++di)
            #pragma unroll
            for (int dj = 0; dj < 3; ++dj)
                val += wr[di] * wr[dj] * pano_adj(i - 1 + di, j - 1 + dj);
    } else {
        val = pano_adj(i, j);
    }
    return (val == 0.f) ? 0.01f : val;
}

// ---------------- generic f32 tiled GEMM ----------------
// MODE 0 (NT): C[m,n] = sum_k A[m*lda+k] * B[n*ldb+k]
// MODE 1 (NN): C[m,n] = sum_k A[m*lda+k] * B[k*ldb+n]
// M must be a multiple of 64, K a multiple of 8. N guarded.
template<int MODE, bool TANH>
__global__ __launch_bounds__(256) void gemm_f32(
        const float* __restrict__ A, const float* __restrict__ B,
        float* __restrict__ C, int M, int N, int K,
        int lda, int ldb, int ldc) {
    __shared__ float As[8][68];
    __shared__ float Bs[8][68];
    const int t  = threadIdx.x;
    const int tx = t & 15, ty = t >> 4;
    const int m0 = blockIdx.y * 64, n0 = blockIdx.x * 64;

    float acc[4][4] = {{0.f}};

    for (int k0 = 0; k0 < K; k0 += 8) {
        if (t < 128) {
            int r = t >> 1, kq = (t & 1) * 4;
            const float4v v = *(const float4v*)(A + (size_t)(m0 + r) * lda + k0 + kq);
            As[kq + 0][r] = v[0]; As[kq + 1][r] = v[1];
            As[kq + 2][r] = v[2]; As[kq + 3][r] = v[3];
        } else {
            int tt = t - 128;
            if (MODE == 0) {
                int nn = tt >> 1, kq = (tt & 1) * 4;
                int gn = n0 + nn;
                float4v v = {0.f, 0.f, 0.f, 0.f};
                if (gn < N) v = *(const float4v*)(B + (size_t)gn * ldb + k0 + kq);
                Bs[kq + 0][nn] = v[0]; Bs[kq + 1][nn] = v[1];
                Bs[kq + 2][nn] = v[2]; Bs[kq + 3][nn] = v[3];
            } else {
                int kk = tt >> 4, nq = (tt & 15) * 4;
                int gn = n0 + nq;
                float4v v = {0.f, 0.f, 0.f, 0.f};
                if (gn < N) v = *(const float4v*)(B + (size_t)(k0 + kk) * ldb + gn);
                *(float4v*)&Bs[kk][nq] = v;
            }
        }
        __syncthreads();
        #pragma unroll
        for (int kk = 0; kk < 8; ++kk) {
            float4v a = *(const float4v*)&As[kk][ty * 4];
            float4v b = *(const float4v*)&Bs[kk][tx * 4];
            #pragma unroll
            for (int i = 0; i < 4; ++i)
                #pragma unroll
                for (int j = 0; j < 4; ++j)
                    acc[i][j] += a[i] * b[j];
        }
        __syncthreads();
    }

    #pragma unroll
    for (int i = 0; i < 4; ++i) {
        int row = m0 + ty * 4 + i;
        #pragma unroll
        for (int j = 0; j < 4; ++j) {
            int col = n0 + tx * 4 + j;
            if (col < N) {
                float v = acc[i][j];
                if (TANH) v = tanhf(v);
                C[(size_t)row * ldc + col] = v;
            }
        }
    }
}

// ---------------- per-row attention kernel ----------------
// One block per b (1024 blocks). Computes energy -> softmax -> attn out,
// attn*pano, weighted context into h[:, 0:1576], copies kv into h[:, 2088:2200].
__global__ __launch_bounds__(256) void attn_wc_kernel(
        const float* __restrict__ V, const float* __restrict__ P,
        const int* __restrict__ tid, const float* __restrict__ kv,
        float* __restrict__ h, float* __restrict__ attn_out) {
    const int b = blockIdx.x;
    const int t = threadIdx.x;
    __shared__ float Pl[CD];
    __shared__ float en[NV];
    __shared__ float ag[NV];

    for (int c = t; c < CD; c += 256) Pl[c] = P[(size_t)b * CD + c];
    __syncthreads();

    const float* Vb = V + (size_t)b * NV * CD;
    const int w = t >> 6, lane = t & 63;

    for (int n = w; n < NV; n += 4) {
        const float* vr = Vb + (size_t)n * CD;
        float s = 0.f;
        for (int c = lane; c < CD; c += 64) s += vr[c] * Pl[c];
        #pragma unroll
        for (int off = 32; off > 0; off >>= 1) s += __shfl_down(s, off);
        if (lane == 0) en[n] = s;
    }
    __syncthreads();

    if (t < 64) {
        const float SCALE = 0.044194173824159216f;  // 512^-0.5
        float e = (t < NV) ? en[t] * SCALE : -1e30f;
        float m = e;
        #pragma unroll
        for (int off = 32; off > 0; off >>= 1) m = fmaxf(m, __shfl_xor(m, off));
        float p = (t < NV) ? __expf(e - m) : 0.f;
        float s = p;
        #pragma unroll
        for (int off = 32; off > 0; off >>= 1) s += __shfl_xor(s, off);
        float a = p / s;
        if (t < NV) {
            attn_out[(size_t)b * NV + t] = a;
            ag[t] = a * pano_entry(tid[b], t);
        }
    }
    __syncthreads();

    for (int c = t; c < CD; c += 256) {
        float s = 0.f;
        #pragma unroll
        for (int n = 0; n < NV; ++n) s += ag[n] * Vb[(size_t)n * CD + c];
        h[(size_t)b * HLD + c] = s;
    }
    for (int j = t; j < KVD; j += 256)
        h[(size_t)b * HLD + (CD + QD) + j] = kv[(size_t)b * KVD + j];
}

extern "C" void kernel_launch(void* const* d_in, const int* in_sizes, int n_in,
                              void* d_out, int out_size, void* d_ws, size_t ws_size,
                              hipStream_t stream) {
    const float* Q   = (const float*)d_in[0];
    const float* V   = (const float*)d_in[1];
    // d_in[2] = detect_feats: provably irrelevant (softmax shift invariance)
    const float* kv  = (const float*)d_in[3];
    const int*   tid = (const int*)  d_in[4];
    const float* Wk  = (const float*)d_in[5];
    const float* Wq  = (const float*)d_in[6];
    const float* Wo  = (const float*)d_in[7];

    float* h = (float*)d_ws;                       // (1024, 2200): [wc | Qf | kv]
    float* P = h + (size_t)BA * HLD;               // (1024, 1576)

    float* out      = (float*)d_out;               // h_tilde (1024, 512)
    float* attn_out = out + (size_t)BA * QD;       // attn    (1024, 36)

    // 1) Qf = Q @ Wq^T  -> h[:, 1576:2088]
    gemm_f32<0, false><<<dim3(QD / 64, BA / 64), 256, 0, stream>>>(
        Q, Wq, h + CD, BA, QD, QD, QD, QD, HLD);

    // 2) P = Qf @ Wk[:, :1576]  (NN)
    gemm_f32<1, false><<<dim3((CD + 63) / 64, BA / 64), 256, 0, stream>>>(
        h + CD, Wk, P, BA, CD, QD, HLD, WKLD, CD);

    // 3) energy/softmax/pano/weighted-context + kv copy
    attn_wc_kernel<<<BA, 256, 0, stream>>>(V, P, tid, kv, h, attn_out);

    // 4) h_tilde = tanh(h @ Wo^T)
    gemm_f32<0, true><<<dim3(QD / 64, BA / 64), 256, 0, stream>>>(
        h, Wo, out, BA, QD, HLD, HLD, HLD, QD);
}

// Round 2
// 153.919 us; speedup vs baseline: 2.7656x; 2.7656x over previous
//
#include <hip/hip_runtime.h>
#include <hip/hip_bf16.h>
#include <math.h>

typedef float f32x4 __attribute__((ext_vector_type(4)));
typedef short short8 __attribute__((ext_vector_type(8)));

#define BA 1024          // B*L
#define QD 512           // QUERY_DIM
#define CD 1576          // CTX_DIM
#define NV 36            // N_VIEWS
#define KVD 112
#define HLD 2200         // 1576 + 512 + 112
#define WKLD 2476        // W_key leading dim
#define CD4 394          // CD / 4

// ---------------- pano affinity, closed form ----------------
__device__ __forceinline__ float pano_adj(int v, int w) {
    if (v == w) return 1.f;
    int rv = v / 12, rw = w / 12;
    int dr = rv - rw; if (dr < 0) dr = -dr;
    if (dr > 1) return 0.f;
    int dc = ((v % 12) - (w % 12) + 12) % 12;
    if (dc == 1 || dc == 11) return 1.f;
    if (dc == 0 && dr == 1) return 1.f;
    return 0.f;
}

__device__ __forceinline__ float pano_entry(int i, int j) {
    if (i == j) return 1.0f;
    float val;
    if (i >= 1 && i <= 34 && j >= 1 && j <= 34) {
        float wr[3] = {0.25f, 0.5f, 0.25f};
        val = 0.f;
        #pragma unroll
        for (int di = 0; di < 3; ++di)
            #pragma unroll
            for (int dj = 0; dj < 3; ++dj)
                val += wr[di] * wr[dj] * pano_adj(i - 1 + di, j - 1 + dj);
    } else {
        val = pano_adj(i, j);
    }
    return (val == 0.f) ? 0.01f : val;
}

__device__ __forceinline__ short f2bf(float f) {
    __hip_bfloat16 h = __float2bfloat16(f);   // RTNE
    union { __hip_bfloat16 b; short s; } u; u.b = h; return u.s;
}

// ---------------- bf16-MFMA GEMM, f32 in / f32 out ----------------
// MODE 0 (NT): C[m,n] = sum_k A[m*lda+k] * B[n*ldb+k]
// MODE 1 (NN): C[m,n] = sum_k A[m*lda+k] * B[k*ldb+n]
// Tile 64x64, BK=32, 4 waves. M multiple of 64. N,K guarded.
// Inputs converted f32->bf16 in-register during LDS staging.
// LDS layout: row-major [64][32] bf16, XOR-swizzled: shortidx ^= ((row&3)<<3)
// (4-way spread of the per-row 16B slots -> ds_read conflict <= 4-way).
template<int MODE, bool TANH>
__global__ __launch_bounds__(256) void gemm_bf16(
        const float* __restrict__ A, const float* __restrict__ B,
        float* __restrict__ C, int M, int N, int K,
        int lda, int ldb, int ldc) {
    __shared__ __align__(16) short As[2][64 * 32];
    __shared__ __align__(16) short Bs[2][64 * 32];
    const int t = threadIdx.x;
    const int lane = t & 63, w = t >> 6;
    const int m0 = blockIdx.y * 64, n0 = blockIdx.x * 64;

    // staging coords (NT: same for A and B; NN-B uses bn/bkq)
    const int sr  = t >> 2;         // 0..63 row
    const int skq = (t & 3) * 8;    // k offset within 32
    const int bn  = t & 63;         // NN: column within tile
    const int bkq = (t >> 6) * 8;   // NN: k offset

    float areg[8], breg[8];

    auto loadA = [&](int k0) {
        const float* src = A + (size_t)(m0 + sr) * lda + k0 + skq;
        if (k0 + skq + 8 <= K) {
            f32x4 v0 = *(const f32x4*)src, v1 = *(const f32x4*)(src + 4);
            areg[0]=v0.x; areg[1]=v0.y; areg[2]=v0.z; areg[3]=v0.w;
            areg[4]=v1.x; areg[5]=v1.y; areg[6]=v1.z; areg[7]=v1.w;
        } else {
            #pragma unroll
            for (int j = 0; j < 8; ++j)
                areg[j] = (k0 + skq + j < K) ? src[j] : 0.f;
        }
    };
    auto loadB = [&](int k0) {
        if (MODE == 0) {
            const float* src = B + (size_t)(n0 + sr) * ldb + k0 + skq;
            bool rowok = (n0 + sr) < N;
            if (rowok && k0 + skq + 8 <= K) {
                f32x4 v0 = *(const f32x4*)src, v1 = *(const f32x4*)(src + 4);
                breg[0]=v0.x; breg[1]=v0.y; breg[2]=v0.z; breg[3]=v0.w;
                breg[4]=v1.x; breg[5]=v1.y; breg[6]=v1.z; breg[7]=v1.w;
            } else {
                #pragma unroll
                for (int j = 0; j < 8; ++j)
                    breg[j] = (rowok && k0 + skq + j < K) ? src[j] : 0.f;
            }
        } else {
            bool colok = (n0 + bn) < N;
            #pragma unroll
            for (int j = 0; j < 8; ++j) {
                int k = k0 + bkq + j;
                breg[j] = (colok && k < K) ? B[(size_t)k * ldb + n0 + bn] : 0.f;
            }
        }
    };
    auto writeAB = [&](int buf) {
        short8 sa, sb;
        #pragma unroll
        for (int j = 0; j < 8; ++j) { sa[j] = f2bf(areg[j]); sb[j] = f2bf(breg[j]); }
        *(short8*)&As[buf][sr * 32 + (skq ^ ((sr & 3) << 3))] = sa;
        if (MODE == 0) {
            *(short8*)&Bs[buf][sr * 32 + (skq ^ ((sr & 3) << 3))] = sb;
        } else {
            *(short8*)&Bs[buf][bn * 32 + (bkq ^ ((bn & 3) << 3))] = sb;
        }
    };

    // fragment LDS indices (per wave quadrant)
    const int wm = (w >> 1) * 32, wn = (w & 1) * 32;
    const int kb = (lane >> 4) * 8;
    int aidx[2], bidx[2];
    #pragma unroll
    for (int i = 0; i < 2; ++i) {
        int ra = wm + i * 16 + (lane & 15);
        int rb = wn + i * 16 + (lane & 15);
        aidx[i] = ra * 32 + (kb ^ ((ra & 3) << 3));
        bidx[i] = rb * 32 + (kb ^ ((rb & 3) << 3));
    }

    f32x4 acc[2][2] = {{{0.f,0.f,0.f,0.f},{0.f,0.f,0.f,0.f}},
                       {{0.f,0.f,0.f,0.f},{0.f,0.f,0.f,0.f}}};

    const int nk = (K + 31) / 32;
    loadA(0); loadB(0); writeAB(0);
    __syncthreads();

    int cur = 0;
    for (int kt = 0; kt < nk; ++kt) {
        const bool more = (kt + 1 < nk);
        if (more) { loadA((kt + 1) * 32); loadB((kt + 1) * 32); }  // prefetch -> regs

        short8 a0 = *(short8*)&As[cur][aidx[0]];
        short8 a1 = *(short8*)&As[cur][aidx[1]];
        short8 b0 = *(short8*)&Bs[cur][bidx[0]];
        short8 b1 = *(short8*)&Bs[cur][bidx[1]];
        acc[0][0] = __builtin_amdgcn_mfma_f32_16x16x32_bf16(a0, b0, acc[0][0], 0, 0, 0);
        acc[0][1] = __builtin_amdgcn_mfma_f32_16x16x32_bf16(a0, b1, acc[0][1], 0, 0, 0);
        acc[1][0] = __builtin_amdgcn_mfma_f32_16x16x32_bf16(a1, b0, acc[1][0], 0, 0, 0);
        acc[1][1] = __builtin_amdgcn_mfma_f32_16x16x32_bf16(a1, b1, acc[1][1], 0, 0, 0);

        if (more) writeAB(cur ^ 1);   // compiler inserts vmcnt before use of regs
        __syncthreads();
        cur ^= 1;
    }

    // epilogue: C/D map: col = lane&15, row = (lane>>4)*4 + reg   [m89 verified]
    #pragma unroll
    for (int mi = 0; mi < 2; ++mi) {
        #pragma unroll
        for (int ni = 0; ni < 2; ++ni) {
            int row = m0 + wm + mi * 16 + (lane >> 4) * 4;
            int col = n0 + wn + ni * 16 + (lane & 15);
            if (col < N) {
                #pragma unroll
                for (int r = 0; r < 4; ++r) {
                    float v = acc[mi][ni][r];
                    if (TANH) v = tanhf(v);
                    C[(size_t)(row + r) * ldc + col] = v;
                }
            }
        }
    }
}

// ---------------- per-row attention kernel (float4-vectorized) ----------------
__global__ __launch_bounds__(256) void attn_wc_kernel(
        const float* __restrict__ V, const float* __restrict__ P,
        const int* __restrict__ tid, const float* __restrict__ kv,
        float* __restrict__ h, float* __restrict__ attn_out) {
    const int b = blockIdx.x;
    const int t = threadIdx.x;
    __shared__ f32x4 Pl[CD4];
    __shared__ float en[NV];
    __shared__ float ag[NV];

    const f32x4* P4 = (const f32x4*)(P + (size_t)b * CD);
    for (int c = t; c < CD4; c += 256) Pl[c] = P4[c];
    __syncthreads();

    const f32x4* V4 = (const f32x4*)(V + (size_t)b * NV * CD);
    const int w = t >> 6, lane = t & 63;

    // pass 1: energies
    for (int n = w; n < NV; n += 4) {
        const f32x4* vr = V4 + (size_t)n * CD4;
        float s = 0.f;
        for (int c = lane; c < CD4; c += 64) {
            f32x4 v = vr[c], p = Pl[c];
            s += v.x * p.x + v.y * p.y + v.z * p.z + v.w * p.w;
        }
        #pragma unroll
        for (int off = 32; off > 0; off >>= 1) s += __shfl_down(s, off);
        if (lane == 0) en[n] = s;
    }
    __syncthreads();

    // softmax + pano gating (first wave)
    if (t < 64) {
        const float SCALE = 0.044194173824159216f;  // 512^-0.5
        float e = (t < NV) ? en[t] * SCALE : -1e30f;
        float m = e;
        #pragma unroll
        for (int off = 32; off > 0; off >>= 1) m = fmaxf(m, __shfl_xor(m, off));
        float p = (t < NV) ? __expf(e - m) : 0.f;
        float s = p;
        #pragma unroll
        for (int off = 32; off > 0; off >>= 1) s += __shfl_xor(s, off);
        float a = p / s;
        if (t < NV) {
            attn_out[(size_t)b * NV + t] = a;
            ag[t] = a * pano_entry(tid[b], t);
        }
    }
    __syncthreads();

    // pass 2: weighted context -> h[:, 0:1576]
    float* hb = h + (size_t)b * HLD;
    for (int c = t; c < CD4; c += 256) {
        f32x4 s = {0.f, 0.f, 0.f, 0.f};
        #pragma unroll
        for (int n = 0; n < NV; ++n) {
            f32x4 v = V4[(size_t)n * CD4 + c];
            float a = ag[n];
            s.x += a * v.x; s.y += a * v.y; s.z += a * v.z; s.w += a * v.w;
        }
        *(f32x4*)(hb + c * 4) = s;
    }
    // kv copy -> h[:, 2088:2200]  (112 f32 = 28 float4)
    if (t < 28)
        ((f32x4*)(hb + CD + QD))[t] = ((const f32x4*)(kv + (size_t)b * KVD))[t];
}

extern "C" void kernel_launch(void* const* d_in, const int* in_sizes, int n_in,
                              void* d_out, int out_size, void* d_ws, size_t ws_size,
                              hipStream_t stream) {
    const float* Q   = (const float*)d_in[0];
    const float* V   = (const float*)d_in[1];
    // d_in[2] = detect_feats: irrelevant (constant over views + softmax shift invariance)
    const float* kv  = (const float*)d_in[3];
    const int*   tid = (const int*)  d_in[4];
    const float* Wk  = (const float*)d_in[5];
    const float* Wq  = (const float*)d_in[6];
    const float* Wo  = (const float*)d_in[7];

    float* h = (float*)d_ws;                       // (1024, 2200): [wc | Qf | kv]
    float* P = h + (size_t)BA * HLD;               // (1024, 1576)

    float* out      = (float*)d_out;               // h_tilde (1024, 512)
    float* attn_out = out + (size_t)BA * QD;       // attn    (1024, 36)

    // 1) Qf = Q @ Wq^T  (NT) -> h[:, 1576:2088]
    gemm_bf16<0, false><<<dim3(QD / 64, BA / 64), 256, 0, stream>>>(
        Q, Wq, h + CD, BA, QD, QD, QD, QD, HLD);

    // 2) P = Qf @ Wk[:, :1576]  (NN)
    gemm_bf16<1, false><<<dim3((CD + 63) / 64, BA / 64), 256, 0, stream>>>(
        h + CD, Wk, P, BA, CD, QD, HLD, WKLD, CD);

    // 3) energy/softmax/pano/weighted-context + kv copy
    attn_wc_kernel<<<BA, 256, 0, stream>>>(V, P, tid, kv, h, attn_out);

    // 4) h_tilde = tanh(h @ Wo^T)  (NT)
    gemm_bf16<0, true><<<dim3(QD / 64, BA / 64), 256, 0, stream>>>(
        h, Wo, out, BA, QD, HLD, HLD, HLD, QD);
}

// Round 3
// 127.498 us; speedup vs baseline: 3.3387x; 1.2072x over previous
//
#include <hip/hip_runtime.h>
#include <hip/hip_bf16.h>
#include <math.h>

typedef float f32x4 __attribute__((ext_vector_type(4)));
typedef short short8 __attribute__((ext_vector_type(8)));
typedef short short4v __attribute__((ext_vector_type(4)));

#define BA 1024          // B*L
#define QD 512           // QUERY_DIM
#define CD 1576          // CTX_DIM
#define NV 36            // N_VIEWS
#define KVD 112
#define HLD 2200         // 1576 + 512 + 112  (bf16 elements)
#define WKLD 2476        // W_key leading dim
#define CD4 394          // CD / 4
#define LDP 72           // LDS pitch (shorts) for 64-k rows: 144B row pitch
                         // -> rows rotate banks by 4; b128 reads/writes hit the
                         // structural 8-lane/bank-group minimum (conflict-free)

// ---------------- pano affinity, closed form ----------------
__device__ __forceinline__ float pano_adj(int v, int w) {
    if (v == w) return 1.f;
    int rv = v / 12, rw = w / 12;
    int dr = rv - rw; if (dr < 0) dr = -dr;
    if (dr > 1) return 0.f;
    int dc = ((v % 12) - (w % 12) + 12) % 12;
    if (dc == 1 || dc == 11) return 1.f;
    if (dc == 0 && dr == 1) return 1.f;
    return 0.f;
}

__device__ __forceinline__ float pano_entry(int i, int j) {
    if (i == j) return 1.0f;
    float val;
    if (i >= 1 && i <= 34 && j >= 1 && j <= 34) {
        float wr[3] = {0.25f, 0.5f, 0.25f};
        val = 0.f;
        #pragma unroll
        for (int di = 0; di < 3; ++di)
            #pragma unroll
            for (int dj = 0; dj < 3; ++dj)
                val += wr[di] * wr[dj] * pano_adj(i - 1 + di, j - 1 + dj);
    } else {
        val = pano_adj(i, j);
    }
    return (val == 0.f) ? 0.01f : val;
}

__device__ __forceinline__ short f2bf(float f) {
    __hip_bfloat16 h = __float2bfloat16(f);   // RTNE
    union { __hip_bfloat16 b; short s; } u; u.b = h; return u.s;
}

// ---------------- bf16-MFMA GEMM ----------------
// MODE 0 (NT): C[m,n] = sum_k A[m*lda+k] * B[n*ldb+k]
// MODE 1 (NN): C[m,n] = sum_k A[m*lda+k] * B[k*ldb+n]   (K must be mult of 64)
// Tile (32*MR) x 64, BK=64, 4 waves (wave does (16*MR) x 32).
// A: f32 or bf16 (ABF16). B: f32 (converted). C: f32 or bf16 (CBF16).
// M multiple of 32*MR; N, K guarded (NT); NN needs K%64==0.
template<int MR, int MODE, bool ABF16, bool CBF16, bool TANH>
__global__ __launch_bounds__(256) void gemm_mfma(
        const void* __restrict__ Av, const float* __restrict__ B,
        void* __restrict__ Cv, int M, int N, int K,
        int lda, int ldb, int ldc) {
    constexpr int BM = 32 * MR;
    __shared__ __align__(16) short As[2][BM * LDP];
    __shared__ __align__(16) short Bs[2][64 * LDP];
    const int t = threadIdx.x;
    const int lane = t & 63, w = t >> 6;
    const int m0 = blockIdx.y * BM, n0 = blockIdx.x * 64;

    const float* Af = (const float*)Av;
    const short* Ah = (const short*)Av;

    // staging coords
    const int ar  = (MR == 2) ? (t >> 2) : (t >> 3);        // A row in tile
    const int akq = (MR == 2) ? ((t & 3) * 16) : ((t & 7) * 8);
    constexpr int AKG = MR;                                  // short8 groups
    const int br  = t >> 2;          // NT: B row in tile
    const int bkq = (t & 3) * 16;
    const int bc  = t & 63;          // NN: B col in tile
    const int bk0 = (t >> 6) * 16;

    short aregh[MR * 8];
    float aregf[MR * 8];
    float breg[16];

    auto loadA = [&](int k0) {
        const size_t rowoff = (size_t)(m0 + ar) * lda;
        #pragma unroll
        for (int g = 0; g < AKG; ++g) {
            int k = k0 + akq + g * 8;
            if (ABF16) {
                if (k + 8 <= K) {
                    *(short8*)&aregh[g * 8] = *(const short8*)(Ah + rowoff + k);
                } else {
                    #pragma unroll
                    for (int j = 0; j < 8; ++j)
                        aregh[g * 8 + j] = (k + j < K) ? Ah[rowoff + k + j] : (short)0;
                }
            } else {
                if (k + 8 <= K) {
                    f32x4 v0 = *(const f32x4*)(Af + rowoff + k);
                    f32x4 v1 = *(const f32x4*)(Af + rowoff + k + 4);
                    aregf[g*8+0]=v0.x; aregf[g*8+1]=v0.y; aregf[g*8+2]=v0.z; aregf[g*8+3]=v0.w;
                    aregf[g*8+4]=v1.x; aregf[g*8+5]=v1.y; aregf[g*8+6]=v1.z; aregf[g*8+7]=v1.w;
                } else {
                    #pragma unroll
                    for (int j = 0; j < 8; ++j)
                        aregf[g * 8 + j] = (k + j < K) ? Af[rowoff + k + j] : 0.f;
                }
            }
        }
    };
    auto loadB = [&](int k0) {
        if (MODE == 0) {
            const size_t rowoff = (size_t)(n0 + br) * ldb;
            bool rowok = (n0 + br) < N;
            #pragma unroll
            for (int g = 0; g < 2; ++g) {
                int k = k0 + bkq + g * 8;
                if (rowok && k + 8 <= K) {
                    f32x4 v0 = *(const f32x4*)(B + rowoff + k);
                    f32x4 v1 = *(const f32x4*)(B + rowoff + k + 4);
                    breg[g*8+0]=v0.x; breg[g*8+1]=v0.y; breg[g*8+2]=v0.z; breg[g*8+3]=v0.w;
                    breg[g*8+4]=v1.x; breg[g*8+5]=v1.y; breg[g*8+6]=v1.z; breg[g*8+7]=v1.w;
                } else {
                    #pragma unroll
                    for (int j = 0; j < 8; ++j)
                        breg[g * 8 + j] = (rowok && k + j < K) ? B[rowoff + k + j] : 0.f;
                }
            }
        } else {
            bool colok = (n0 + bc) < N;     // NN: K%64==0 assumed
            #pragma unroll
            for (int j = 0; j < 16; ++j)
                breg[j] = colok ? B[(size_t)(k0 + bk0 + j) * ldb + n0 + bc] : 0.f;
        }
    };
    auto writeAB = [&](int buf) {
        #pragma unroll
        for (int g = 0; g < AKG; ++g) {
            short8 sa;
            #pragma unroll
            for (int j = 0; j < 8; ++j)
                sa[j] = ABF16 ? aregh[g * 8 + j] : f2bf(aregf[g * 8 + j]);
            *(short8*)&As[buf][ar * LDP + akq + g * 8] = sa;
        }
        #pragma unroll
        for (int g = 0; g < 2; ++g) {
            short8 sb;
            #pragma unroll
            for (int j = 0; j < 8; ++j) sb[j] = f2bf(breg[g * 8 + j]);
            if (MODE == 0) *(short8*)&Bs[buf][br * LDP + bkq + g * 8] = sb;
            else           *(short8*)&Bs[buf][bc * LDP + bk0 + g * 8] = sb;
        }
    };

    // fragment indices
    const int wm = (w >> 1) * (16 * MR), wn = (w & 1) * 32;
    const int kb = (lane >> 4) * 8;
    int aidx[MR], bidx[2];
    #pragma unroll
    for (int i = 0; i < MR; ++i)
        aidx[i] = (wm + i * 16 + (lane & 15)) * LDP + kb;
    #pragma unroll
    for (int j = 0; j < 2; ++j)
        bidx[j] = (wn + j * 16 + (lane & 15)) * LDP + kb;

    f32x4 acc[MR][2];
    #pragma unroll
    for (int i = 0; i < MR; ++i)
        #pragma unroll
        for (int j = 0; j < 2; ++j) acc[i][j] = (f32x4){0.f, 0.f, 0.f, 0.f};

    const int nk = (K + 63) / 64;
    loadA(0); loadB(0); writeAB(0);
    __syncthreads();

    int cur = 0;
    for (int kt = 0; kt < nk; ++kt) {
        const bool more = (kt + 1 < nk);
        if (more) { loadA((kt + 1) * 64); loadB((kt + 1) * 64); }

        #pragma unroll
        for (int ks = 0; ks < 2; ++ks) {
            short8 afr[MR], bfr[2];
            #pragma unroll
            for (int i = 0; i < MR; ++i) afr[i] = *(short8*)&As[cur][aidx[i] + ks * 32];
            #pragma unroll
            for (int j = 0; j < 2; ++j)  bfr[j] = *(short8*)&Bs[cur][bidx[j] + ks * 32];
            #pragma unroll
            for (int i = 0; i < MR; ++i)
                #pragma unroll
                for (int j = 0; j < 2; ++j)
                    acc[i][j] = __builtin_amdgcn_mfma_f32_16x16x32_bf16(afr[i], bfr[j], acc[i][j], 0, 0, 0);
        }

        if (more) writeAB(cur ^ 1);
        __syncthreads();
        cur ^= 1;
    }

    // epilogue: C/D map: col = lane&15, row = (lane>>4)*4 + reg
    #pragma unroll
    for (int i = 0; i < MR; ++i) {
        #pragma unroll
        for (int j = 0; j < 2; ++j) {
            int row = m0 + wm + i * 16 + (lane >> 4) * 4;
            int col = n0 + wn + j * 16 + (lane & 15);
            if (col < N) {
                #pragma unroll
                for (int r = 0; r < 4; ++r) {
                    float v = acc[i][j][r];
                    if (TANH) v = tanhf(v);
                    if (CBF16) ((short*)Cv)[(size_t)(row + r) * ldc + col] = f2bf(v);
                    else       ((float*)Cv)[(size_t)(row + r) * ldc + col] = v;
                }
            }
        }
    }
}

// ---------------- per-row attention kernel ----------------
// h is bf16: [wc(1576) | Qf(512) | kv(112)] per row.
__global__ __launch_bounds__(256) void attn_wc_kernel(
        const float* __restrict__ V, const float* __restrict__ P,
        const int* __restrict__ tid, const float* __restrict__ kv,
        short* __restrict__ h, float* __restrict__ attn_out) {
    const int b = blockIdx.x;
    const int t = threadIdx.x;
    __shared__ f32x4 Pl[CD4];
    __shared__ float en[NV];
    __shared__ float ag[NV];

    const f32x4* P4 = (const f32x4*)(P + (size_t)b * CD);
    for (int c = t; c < CD4; c += 256) Pl[c] = P4[c];
    __syncthreads();

    const f32x4* V4 = (const f32x4*)(V + (size_t)b * NV * CD);
    const int w = t >> 6, lane = t & 63;

    // pass 1: energies
    for (int n = w; n < NV; n += 4) {
        const f32x4* vr = V4 + (size_t)n * CD4;
        float s = 0.f;
        for (int c = lane; c < CD4; c += 64) {
            f32x4 v = vr[c], p = Pl[c];
            s += v.x * p.x + v.y * p.y + v.z * p.z + v.w * p.w;
        }
        #pragma unroll
        for (int off = 32; off > 0; off >>= 1) s += __shfl_down(s, off);
        if (lane == 0) en[n] = s;
    }
    __syncthreads();

    // softmax + pano gating (first wave)
    if (t < 64) {
        const float SCALE = 0.044194173824159216f;  // 512^-0.5
        float e = (t < NV) ? en[t] * SCALE : -1e30f;
        float m = e;
        #pragma unroll
        for (int off = 32; off > 0; off >>= 1) m = fmaxf(m, __shfl_xor(m, off));
        float p = (t < NV) ? __expf(e - m) : 0.f;
        float s = p;
        #pragma unroll
        for (int off = 32; off > 0; off >>= 1) s += __shfl_xor(s, off);
        float a = p / s;
        if (t < NV) {
            attn_out[(size_t)b * NV + t] = a;
            ag[t] = a * pano_entry(tid[b], t);
        }
    }
    __syncthreads();

    // pass 2: weighted context -> h[:, 0:1576] (bf16)
    short* hb = h + (size_t)b * HLD;
    for (int c = t; c < CD4; c += 256) {
        f32x4 s = {0.f, 0.f, 0.f, 0.f};
        #pragma unroll
        for (int n = 0; n < NV; ++n) {
            f32x4 v = V4[(size_t)n * CD4 + c];
            float a = ag[n];
            s.x += a * v.x; s.y += a * v.y; s.z += a * v.z; s.w += a * v.w;
        }
        short4v o = { f2bf(s.x), f2bf(s.y), f2bf(s.z), f2bf(s.w) };
        *(short4v*)(hb + c * 4) = o;
    }
    // kv -> h[:, 2088:2200] (bf16)
    if (t < KVD)
        hb[CD + QD + t] = f2bf(kv[(size_t)b * KVD + t]);
}

extern "C" void kernel_launch(void* const* d_in, const int* in_sizes, int n_in,
                              void* d_out, int out_size, void* d_ws, size_t ws_size,
                              hipStream_t stream) {
    const float* Q   = (const float*)d_in[0];
    const float* V   = (const float*)d_in[1];
    // d_in[2] = detect_feats: irrelevant (constant over views + softmax shift invariance)
    const float* kv  = (const float*)d_in[3];
    const int*   tid = (const int*)  d_in[4];
    const float* Wk  = (const float*)d_in[5];
    const float* Wq  = (const float*)d_in[6];
    const float* Wo  = (const float*)d_in[7];

    short* h = (short*)d_ws;                        // (1024, 2200) bf16
    float* P = (float*)(h + (size_t)BA * HLD);      // (1024, 1576) f32

    float* out      = (float*)d_out;                // h_tilde (1024, 512)
    float* attn_out = out + (size_t)BA * QD;        // attn    (1024, 36)

    // 1) Qf = Q @ Wq^T (NT, A f32, C bf16) -> h[:, 1576:2088]
    gemm_mfma<1, 0, false, true, false><<<dim3(QD / 64, BA / 32), 256, 0, stream>>>(
        Q, Wq, h + CD, BA, QD, QD, QD, QD, HLD);

    // 2) P = Qf @ Wk[:, :1576] (NN, A bf16, C f32)
    gemm_mfma<2, 1, true, false, false><<<dim3((CD + 63) / 64, BA / 64), 256, 0, stream>>>(
        h + CD, Wk, P, BA, CD, QD, HLD, WKLD, CD);

    // 3) energy/softmax/pano/weighted-context + kv copy
    attn_wc_kernel<<<BA, 256, 0, stream>>>(V, P, tid, kv, h, attn_out);

    // 4) h_tilde = tanh(h @ Wo^T) (NT, A bf16, C f32)
    gemm_mfma<1, 0, true, false, true><<<dim3(QD / 64, BA / 32), 256, 0, stream>>>(
        h, Wo, out, BA, QD, HLD, HLD, HLD, QD);
}

// Round 4
// 105.054 us; speedup vs baseline: 4.0520x; 1.2136x over previous
//
#include <hip/hip_runtime.h>
#include <hip/hip_bf16.h>
#include <math.h>

typedef float f32x4 __attribute__((ext_vector_type(4)));
typedef short short8 __attribute__((ext_vector_type(8)));
typedef short short4v __attribute__((ext_vector_type(4)));

#define BA 1024          // B*L
#define QD 512           // QUERY_DIM
#define CD 1576          // CTX_DIM
#define NV 36            // N_VIEWS
#define KVD 112
#define HLD 2200         // 1576 + 512 + 112  (bf16 elements)
#define WKLD 2476        // W_key leading dim
#define CD4 394          // CD / 4
#define LDP 72           // GEMM LDS pitch (shorts): 144B rows rotate 4 banks

// ---------------- pano affinity, closed form ----------------
__device__ __forceinline__ float pano_adj(int v, int w) {
    if (v == w) return 1.f;
    int rv = v / 12, rw = w / 12;
    int dr = rv - rw; if (dr < 0) dr = -dr;
    if (dr > 1) return 0.f;
    int dc = ((v % 12) - (w % 12) + 12) % 12;
    if (dc == 1 || dc == 11) return 1.f;
    if (dc == 0 && dr == 1) return 1.f;
    return 0.f;
}

__device__ __forceinline__ float pano_entry(int i, int j) {
    if (i == j) return 1.0f;
    float val;
    if (i >= 1 && i <= 34 && j >= 1 && j <= 34) {
        float wr[3] = {0.25f, 0.5f, 0.25f};
        val = 0.f;
        #pragma unroll
        for (int di = 0; di < 3; ++di)
            #pragma unroll
            for (int dj = 0; dj < 3; ++dj)
                val += wr[di] * wr[dj] * pano_adj(i - 1 + di, j - 1 + dj);
    } else {
        val = pano_adj(i, j);
    }
    return (val == 0.f) ? 0.01f : val;
}

__device__ __forceinline__ short f2bf(float f) {
    __hip_bfloat16 h = __float2bfloat16(f);   // RTNE
    union { __hip_bfloat16 b; short s; } u; u.b = h; return u.s;
}

// ---------------- bf16-MFMA GEMM (unchanged from R3) ----------------
template<int MR, int MODE, bool ABF16, bool CBF16, bool TANH>
__global__ __launch_bounds__(256) void gemm_mfma(
        const void* __restrict__ Av, const float* __restrict__ B,
        void* __restrict__ Cv, int M, int N, int K,
        int lda, int ldb, int ldc) {
    constexpr int BM = 32 * MR;
    __shared__ __align__(16) short As[2][BM * LDP];
    __shared__ __align__(16) short Bs[2][64 * LDP];
    const int t = threadIdx.x;
    const int lane = t & 63, w = t >> 6;
    const int m0 = blockIdx.y * BM, n0 = blockIdx.x * 64;

    const float* Af = (const float*)Av;
    const short* Ah = (const short*)Av;

    const int ar  = (MR == 2) ? (t >> 2) : (t >> 3);
    const int akq = (MR == 2) ? ((t & 3) * 16) : ((t & 7) * 8);
    constexpr int AKG = MR;
    const int br  = t >> 2;
    const int bkq = (t & 3) * 16;
    const int bc  = t & 63;
    const int bk0 = (t >> 6) * 16;

    short aregh[MR * 8];
    float aregf[MR * 8];
    float breg[16];

    auto loadA = [&](int k0) {
        const size_t rowoff = (size_t)(m0 + ar) * lda;
        #pragma unroll
        for (int g = 0; g < AKG; ++g) {
            int k = k0 + akq + g * 8;
            if (ABF16) {
                if (k + 8 <= K) {
                    *(short8*)&aregh[g * 8] = *(const short8*)(Ah + rowoff + k);
                } else {
                    #pragma unroll
                    for (int j = 0; j < 8; ++j)
                        aregh[g * 8 + j] = (k + j < K) ? Ah[rowoff + k + j] : (short)0;
                }
            } else {
                if (k + 8 <= K) {
                    f32x4 v0 = *(const f32x4*)(Af + rowoff + k);
                    f32x4 v1 = *(const f32x4*)(Af + rowoff + k + 4);
                    aregf[g*8+0]=v0.x; aregf[g*8+1]=v0.y; aregf[g*8+2]=v0.z; aregf[g*8+3]=v0.w;
                    aregf[g*8+4]=v1.x; aregf[g*8+5]=v1.y; aregf[g*8+6]=v1.z; aregf[g*8+7]=v1.w;
                } else {
                    #pragma unroll
                    for (int j = 0; j < 8; ++j)
                        aregf[g * 8 + j] = (k + j < K) ? Af[rowoff + k + j] : 0.f;
                }
            }
        }
    };
    auto loadB = [&](int k0) {
        if (MODE == 0) {
            const size_t rowoff = (size_t)(n0 + br) * ldb;
            bool rowok = (n0 + br) < N;
            #pragma unroll
            for (int g = 0; g < 2; ++g) {
                int k = k0 + bkq + g * 8;
                if (rowok && k + 8 <= K) {
                    f32x4 v0 = *(const f32x4*)(B + rowoff + k);
                    f32x4 v1 = *(const f32x4*)(B + rowoff + k + 4);
                    breg[g*8+0]=v0.x; breg[g*8+1]=v0.y; breg[g*8+2]=v0.z; breg[g*8+3]=v0.w;
                    breg[g*8+4]=v1.x; breg[g*8+5]=v1.y; breg[g*8+6]=v1.z; breg[g*8+7]=v1.w;
                } else {
                    #pragma unroll
                    for (int j = 0; j < 8; ++j)
                        breg[g * 8 + j] = (rowok && k + j < K) ? B[rowoff + k + j] : 0.f;
                }
            }
        } else {
            bool colok = (n0 + bc) < N;     // NN: K%64==0 assumed
            #pragma unroll
            for (int j = 0; j < 16; ++j)
                breg[j] = colok ? B[(size_t)(k0 + bk0 + j) * ldb + n0 + bc] : 0.f;
        }
    };
    auto writeAB = [&](int buf) {
        #pragma unroll
        for (int g = 0; g < AKG; ++g) {
            short8 sa;
            #pragma unroll
            for (int j = 0; j < 8; ++j)
                sa[j] = ABF16 ? aregh[g * 8 + j] : f2bf(aregf[g * 8 + j]);
            *(short8*)&As[buf][ar * LDP + akq + g * 8] = sa;
        }
        #pragma unroll
        for (int g = 0; g < 2; ++g) {
            short8 sb;
            #pragma unroll
            for (int j = 0; j < 8; ++j) sb[j] = f2bf(breg[g * 8 + j]);
            if (MODE == 0) *(short8*)&Bs[buf][br * LDP + bkq + g * 8] = sb;
            else           *(short8*)&Bs[buf][bc * LDP + bk0 + g * 8] = sb;
        }
    };

    const int wm = (w >> 1) * (16 * MR), wn = (w & 1) * 32;
    const int kb = (lane >> 4) * 8;
    int aidx[MR], bidx[2];
    #pragma unroll
    for (int i = 0; i < MR; ++i)
        aidx[i] = (wm + i * 16 + (lane & 15)) * LDP + kb;
    #pragma unroll
    for (int j = 0; j < 2; ++j)
        bidx[j] = (wn + j * 16 + (lane & 15)) * LDP + kb;

    f32x4 acc[MR][2];
    #pragma unroll
    for (int i = 0; i < MR; ++i)
        #pragma unroll
        for (int j = 0; j < 2; ++j) acc[i][j] = (f32x4){0.f, 0.f, 0.f, 0.f};

    const int nk = (K + 63) / 64;
    loadA(0); loadB(0); writeAB(0);
    __syncthreads();

    int cur = 0;
    for (int kt = 0; kt < nk; ++kt) {
        const bool more = (kt + 1 < nk);
        if (more) { loadA((kt + 1) * 64); loadB((kt + 1) * 64); }

        #pragma unroll
        for (int ks = 0; ks < 2; ++ks) {
            short8 afr[MR], bfr[2];
            #pragma unroll
            for (int i = 0; i < MR; ++i) afr[i] = *(short8*)&As[cur][aidx[i] + ks * 32];
            #pragma unroll
            for (int j = 0; j < 2; ++j)  bfr[j] = *(short8*)&Bs[cur][bidx[j] + ks * 32];
            #pragma unroll
            for (int i = 0; i < MR; ++i)
                #pragma unroll
                for (int j = 0; j < 2; ++j)
                    acc[i][j] = __builtin_amdgcn_mfma_f32_16x16x32_bf16(afr[i], bfr[j], acc[i][j], 0, 0, 0);
        }

        if (more) writeAB(cur ^ 1);
        __syncthreads();
        cur ^= 1;
    }

    #pragma unroll
    for (int i = 0; i < MR; ++i) {
        #pragma unroll
        for (int j = 0; j < 2; ++j) {
            int row = m0 + wm + i * 16 + (lane >> 4) * 4;
            int col = n0 + wn + j * 16 + (lane & 15);
            if (col < N) {
                #pragma unroll
                for (int r = 0; r < 4; ++r) {
                    float v = acc[i][j][r];
                    if (TANH) v = tanhf(v);
                    if (CBF16) ((short*)Cv)[(size_t)(row + r) * ldc + col] = f2bf(v);
                    else       ((float*)Cv)[(size_t)(row + r) * ldc + col] = v;
                }
            }
        }
    }
}

// ---------------- one-pass attention: V held in registers ----------------
// 512 threads (8 waves) per b. Wave w owns rows {w, w+8, ...} (5 rows max).
// Per-lane: 7 f32x4 chunks per row (chunk c = lane + 64*j over CD4=394).
// V is read from HBM exactly once.
#define NR 5
#define NCH 7
__global__ __launch_bounds__(512, 2) void attn_wc_onepass(
        const float* __restrict__ V, const float* __restrict__ P,
        const int* __restrict__ tid, const float* __restrict__ kv,
        short* __restrict__ h, float* __restrict__ attn_out) {
    const int b = blockIdx.x;
    const int t = threadIdx.x;
    const int w = t >> 6, lane = t & 63;
    __shared__ float en[NV];
    __shared__ float ag[NV];
    __shared__ __align__(16) f32x4 part[8 * 448];   // 57 KB

    const f32x4* V4 = (const f32x4*)(V + (size_t)b * NV * CD);
    const f32x4* P4 = (const f32x4*)(P + (size_t)b * CD);

    // P chunks (per-lane positions shared by all rows)
    f32x4 p[NCH];
    #pragma unroll
    for (int j = 0; j < NCH; ++j) {
        int c = lane + 64 * j;
        p[j] = (c < CD4) ? P4[c] : (f32x4){0.f, 0.f, 0.f, 0.f};
    }
    // V rows -> registers (single HBM pass)
    f32x4 v[NR][NCH];
    #pragma unroll
    for (int r = 0; r < NR; ++r) {
        int n = w + 8 * r;
        #pragma unroll
        for (int j = 0; j < NCH; ++j) {
            int c = lane + 64 * j;
            v[r][j] = (n < NV && c < CD4) ? V4[(size_t)n * CD4 + c]
                                          : (f32x4){0.f, 0.f, 0.f, 0.f};
        }
    }
    // energies: lane-local dot, wave reduce
    #pragma unroll
    for (int r = 0; r < NR; ++r) {
        float s = 0.f;
        #pragma unroll
        for (int j = 0; j < NCH; ++j) {
            f32x4 vv = v[r][j], pp = p[j];
            s += vv.x * pp.x + vv.y * pp.y + vv.z * pp.z + vv.w * pp.w;
        }
        #pragma unroll
        for (int off = 32; off > 0; off >>= 1) s += __shfl_xor(s, off);
        int n = w + 8 * r;
        if (lane == 0 && n < NV) en[n] = s;
    }
    __syncthreads();

    // softmax + pano gating (wave 0)
    if (t < 64) {
        const float SCALE = 0.044194173824159216f;  // 512^-0.5
        float e = (t < NV) ? en[t] * SCALE : -1e30f;
        float m = e;
        #pragma unroll
        for (int off = 32; off > 0; off >>= 1) m = fmaxf(m, __shfl_xor(m, off));
        float pr = (t < NV) ? __expf(e - m) : 0.f;
        float s = pr;
        #pragma unroll
        for (int off = 32; off > 0; off >>= 1) s += __shfl_xor(s, off);
        float a = pr / s;
        if (t < NV) {
            attn_out[(size_t)b * NV + t] = a;
            ag[t] = a * pano_entry(tid[b], t);
        }
    }
    __syncthreads();

    // weighted context from registers; per-wave partials -> LDS
    f32x4 acc[NCH];
    #pragma unroll
    for (int j = 0; j < NCH; ++j) acc[j] = (f32x4){0.f, 0.f, 0.f, 0.f};
    #pragma unroll
    for (int r = 0; r < NR; ++r) {
        int n = w + 8 * r;
        float a = (n < NV) ? ag[n] : 0.f;
        #pragma unroll
        for (int j = 0; j < NCH; ++j) {
            acc[j].x += a * v[r][j].x; acc[j].y += a * v[r][j].y;
            acc[j].z += a * v[r][j].z; acc[j].w += a * v[r][j].w;
        }
    }
    #pragma unroll
    for (int j = 0; j < NCH; ++j)
        part[w * 448 + lane + 64 * j] = acc[j];
    __syncthreads();

    // cross-wave reduce + bf16 store
    short* hb = h + (size_t)b * HLD;
    if (t < CD4) {
        f32x4 s = part[t];
        #pragma unroll
        for (int w2 = 1; w2 < 8; ++w2) {
            f32x4 q = part[w2 * 448 + t];
            s.x += q.x; s.y += q.y; s.z += q.z; s.w += q.w;
        }
        short4v o = { f2bf(s.x), f2bf(s.y), f2bf(s.z), f2bf(s.w) };
        *(short4v*)(hb + t * 4) = o;
    }
    // kv -> h[:, 2088:2200] (bf16)
    if (t < KVD)
        hb[CD + QD + t] = f2bf(kv[(size_t)b * KVD + t]);
}

extern "C" void kernel_launch(void* const* d_in, const int* in_sizes, int n_in,
                              void* d_out, int out_size, void* d_ws, size_t ws_size,
                              hipStream_t stream) {
    const float* Q   = (const float*)d_in[0];
    const float* V   = (const float*)d_in[1];
    // d_in[2] = detect_feats: irrelevant (constant over views + softmax shift invariance)
    const float* kv  = (const float*)d_in[3];
    const int*   tid = (const int*)  d_in[4];
    const float* Wk  = (const float*)d_in[5];
    const float* Wq  = (const float*)d_in[6];
    const float* Wo  = (const float*)d_in[7];

    short* h = (short*)d_ws;                        // (1024, 2200) bf16
    float* P = (float*)(h + (size_t)BA * HLD);      // (1024, 1576) f32

    float* out      = (float*)d_out;                // h_tilde (1024, 512)
    float* attn_out = out + (size_t)BA * QD;        // attn    (1024, 36)

    // 1) Qf = Q @ Wq^T (NT, A f32, C bf16) -> h[:, 1576:2088]
    gemm_mfma<1, 0, false, true, false><<<dim3(QD / 64, BA / 32), 256, 0, stream>>>(
        Q, Wq, h + CD, BA, QD, QD, QD, QD, HLD);

    // 2) P = Qf @ Wk[:, :1576] (NN, A bf16, C f32)
    gemm_mfma<2, 1, true, false, false><<<dim3((CD + 63) / 64, BA / 64), 256, 0, stream>>>(
        h + CD, Wk, P, BA, CD, QD, HLD, WKLD, CD);

    // 3) energy/softmax/pano/weighted-context + kv copy (V read once)
    attn_wc_onepass<<<BA, 512, 0, stream>>>(V, P, tid, kv, h, attn_out);

    // 4) h_tilde = tanh(h @ Wo^T) (NT, A bf16, C f32)
    gemm_mfma<1, 0, true, false, true><<<dim3(QD / 64, BA / 32), 256, 0, stream>>>(
        h, Wo, out, BA, QD, HLD, HLD, HLD, QD);
}

// Round 5
// 99.192 us; speedup vs baseline: 4.2915x; 1.0591x over previous
//
#include <hip/hip_runtime.h>
#include <hip/hip_bf16.h>
#include <math.h>

typedef float f32x4 __attribute__((ext_vector_type(4)));
typedef short short8 __attribute__((ext_vector_type(8)));
typedef short short4v __attribute__((ext_vector_type(4)));

#define BA 1024          // B*L
#define QD 512           // QUERY_DIM
#define CD 1576          // CTX_DIM
#define NV 36            // N_VIEWS
#define KVD 112
#define HLD 2200         // 1576 + 512 + 112  (bf16 elements)
#define WKLD 2476        // W_key leading dim
#define CD4 394          // CD / 4
#define LDP 72           // GEMM LDS pitch (shorts): 144B rows rotate 4 banks

// ---------------- pano affinity, closed form ----------------
__device__ __forceinline__ float pano_adj(int v, int w) {
    if (v == w) return 1.f;
    int rv = v / 12, rw = w / 12;
    int dr = rv - rw; if (dr < 0) dr = -dr;
    if (dr > 1) return 0.f;
    int dc = ((v % 12) - (w % 12) + 12) % 12;
    if (dc == 1 || dc == 11) return 1.f;
    if (dc == 0 && dr == 1) return 1.f;
    return 0.f;
}

__device__ __forceinline__ float pano_entry(int i, int j) {
    if (i == j) return 1.0f;
    float val;
    if (i >= 1 && i <= 34 && j >= 1 && j <= 34) {
        float wr[3] = {0.25f, 0.5f, 0.25f};
        val = 0.f;
        #pragma unroll
        for (int di = 0; di < 3; ++di)
            #pragma unroll
            for (int dj = 0; dj < 3; ++dj)
                val += wr[di] * wr[dj] * pano_adj(i - 1 + di, j - 1 + dj);
    } else {
        val = pano_adj(i, j);
    }
    return (val == 0.f) ? 0.01f : val;
}

__device__ __forceinline__ short f2bf(float f) {
    __hip_bfloat16 h = __float2bfloat16(f);   // RTNE
    union { __hip_bfloat16 b; short s; } u; u.b = h; return u.s;
}

// ---------------- prep: weights -> bf16 (Wk_v transposed) ----------------
// blocks [0,800): transpose Wk[:, :1576] (512x2476 f32) -> wk_t (1576x512 bf16)
// blocks [800,2156): convert Wq (512x512) -> wq_b, Wo (512x2200) -> wo_b
__global__ __launch_bounds__(256) void prep_weights(
        const float* __restrict__ Wk, const float* __restrict__ Wq,
        const float* __restrict__ Wo, short* __restrict__ wk_t,
        short* __restrict__ wq_b, short* __restrict__ wo_b) {
    __shared__ float tile[32][33];
    const int bx = blockIdx.x, t = threadIdx.x;
    if (bx < 800) {
        const int n0 = (bx % 50) * 32, q0 = (bx / 50) * 32;
        const int tx = t & 31, ty = t >> 5;          // 32 x 8
        #pragma unroll
        for (int i = 0; i < 4; ++i) {
            int r = q0 + ty + i * 8;                 // q row (always < 512)
            int c = n0 + tx;                         // n col (< 1600 < 2476, safe)
            tile[ty + i * 8][tx] = Wk[(size_t)r * WKLD + c];
        }
        __syncthreads();
        #pragma unroll
        for (int i = 0; i < 4; ++i) {
            int n = n0 + ty + i * 8;
            if (n < CD)
                wk_t[(size_t)n * QD + q0 + tx] = f2bf(tile[tx][ty + i * 8]);
        }
    } else {
        int i = (bx - 800) * 256 + t;                // f32x4 chunk index
        const int NWQ = (QD * QD) / 4;               // 65536
        const int NWO = (QD * HLD) / 4;              // 281600
        if (i < NWQ) {
            f32x4 v = ((const f32x4*)Wq)[i];
            short4v o = { f2bf(v.x), f2bf(v.y), f2bf(v.z), f2bf(v.w) };
            ((short4v*)wq_b)[i] = o;
        } else if (i < NWQ + NWO) {
            int j = i - NWQ;
            f32x4 v = ((const f32x4*)Wo)[j];
            short4v o = { f2bf(v.x), f2bf(v.y), f2bf(v.z), f2bf(v.w) };
            ((short4v*)wo_b)[j] = o;
        }
    }
}

// ---------------- bf16-MFMA GEMM, NT, B pre-converted bf16 ----------------
// C[m,n] = sum_k A[m,k] * Bt[n,k].  Tile (32*MR) x 64, BK=64, 4 waves.
// A: f32 or bf16 (ABF16), row-major lda. Bt: bf16, row-major ldb.
// M multiple of 32*MR; N, K guarded.
template<int MR, bool ABF16, bool CBF16, bool TANH>
__global__ __launch_bounds__(256) void gemm_nt(
        const void* __restrict__ Av, const short* __restrict__ Bt,
        void* __restrict__ Cv, int M, int N, int K,
        int lda, int ldb, int ldc) {
    constexpr int BM = 32 * MR;
    constexpr int AG = MR;                 // short8 groups per thread for A
    __shared__ __align__(16) short As[2][BM * LDP];
    __shared__ __align__(16) short Bs[2][64 * LDP];
    const int t = threadIdx.x;
    const int lane = t & 63, w = t >> 6;
    const int m0 = blockIdx.y * BM, n0 = blockIdx.x * 64;
    const float* Af = (const float*)Av;
    const short* Ah = (const short*)Av;

    const int ar  = (MR == 2) ? (t >> 2) : (t >> 3);
    const int akq = (MR == 2) ? ((t & 3) * 16) : ((t & 7) * 8);
    const int br  = t >> 2, bkq = (t & 3) * 16;

    short8 abuf[AG];
    short8 bbuf[2];

    auto loadA = [&](int k0) {
        const size_t ro = (size_t)(m0 + ar) * lda;
        #pragma unroll
        for (int g = 0; g < AG; ++g) {
            int k = k0 + akq + g * 8;
            short8 z;
            if (ABF16) {
                if (k + 8 <= K) z = *(const short8*)(Ah + ro + k);
                else {
                    #pragma unroll
                    for (int j = 0; j < 8; ++j) z[j] = (k + j < K) ? Ah[ro + k + j] : (short)0;
                }
            } else {
                if (k + 8 <= K) {
                    f32x4 v0 = *(const f32x4*)(Af + ro + k);
                    f32x4 v1 = *(const f32x4*)(Af + ro + k + 4);
                    z[0]=f2bf(v0.x); z[1]=f2bf(v0.y); z[2]=f2bf(v0.z); z[3]=f2bf(v0.w);
                    z[4]=f2bf(v1.x); z[5]=f2bf(v1.y); z[6]=f2bf(v1.z); z[7]=f2bf(v1.w);
                } else {
                    #pragma unroll
                    for (int j = 0; j < 8; ++j) z[j] = (k + j < K) ? f2bf(Af[ro + k + j]) : (short)0;
                }
            }
            abuf[g] = z;
        }
    };
    auto loadB = [&](int k0) {
        const int rn = n0 + br;
        const size_t ro = (size_t)rn * ldb;
        const bool ok = rn < N;
        #pragma unroll
        for (int g = 0; g < 2; ++g) {
            int k = k0 + bkq + g * 8;
            short8 z;
            if (ok && k + 8 <= K) z = *(const short8*)(Bt + ro + k);
            else {
                #pragma unroll
                for (int j = 0; j < 8; ++j) z[j] = (ok && k + j < K) ? Bt[ro + k + j] : (short)0;
            }
            bbuf[g] = z;
        }
    };
    auto writeAB = [&](int buf) {
        #pragma unroll
        for (int g = 0; g < AG; ++g)
            *(short8*)&As[buf][ar * LDP + akq + g * 8] = abuf[g];
        #pragma unroll
        for (int g = 0; g < 2; ++g)
            *(short8*)&Bs[buf][br * LDP + bkq + g * 8] = bbuf[g];
    };

    // fragment indices: A-frag lane l holds rows (l&15), k = (l>>4)*8 + j
    const int wm = (w >> 1) * (16 * MR), wn = (w & 1) * 32;
    const int kb = (lane >> 4) * 8;
    int aidx[MR], bidx[2];
    #pragma unroll
    for (int i = 0; i < MR; ++i)
        aidx[i] = (wm + i * 16 + (lane & 15)) * LDP + kb;
    #pragma unroll
    for (int j = 0; j < 2; ++j)
        bidx[j] = (wn + j * 16 + (lane & 15)) * LDP + kb;

    f32x4 acc[MR][2];
    #pragma unroll
    for (int i = 0; i < MR; ++i)
        #pragma unroll
        for (int j = 0; j < 2; ++j) acc[i][j] = (f32x4){0.f, 0.f, 0.f, 0.f};

    const int nk = (K + 63) / 64;
    loadA(0); loadB(0); writeAB(0);
    __syncthreads();

    int cur = 0;
    for (int kt = 0; kt < nk; ++kt) {
        const bool more = (kt + 1 < nk);
        if (more) { loadA((kt + 1) * 64); loadB((kt + 1) * 64); }

        #pragma unroll
        for (int ks = 0; ks < 2; ++ks) {
            short8 afr[MR], bfr[2];
            #pragma unroll
            for (int i = 0; i < MR; ++i) afr[i] = *(short8*)&As[cur][aidx[i] + ks * 32];
            #pragma unroll
            for (int j = 0; j < 2; ++j)  bfr[j] = *(short8*)&Bs[cur][bidx[j] + ks * 32];
            #pragma unroll
            for (int i = 0; i < MR; ++i)
                #pragma unroll
                for (int j = 0; j < 2; ++j)
                    acc[i][j] = __builtin_amdgcn_mfma_f32_16x16x32_bf16(afr[i], bfr[j], acc[i][j], 0, 0, 0);
        }

        if (more) writeAB(cur ^ 1);
        __syncthreads();
        cur ^= 1;
    }

    // epilogue: C/D map: col = lane&15, row = (lane>>4)*4 + reg
    #pragma unroll
    for (int i = 0; i < MR; ++i) {
        #pragma unroll
        for (int j = 0; j < 2; ++j) {
            int row = m0 + wm + i * 16 + (lane >> 4) * 4;
            int col = n0 + wn + j * 16 + (lane & 15);
            if (col < N) {
                #pragma unroll
                for (int r = 0; r < 4; ++r) {
                    float v = acc[i][j][r];
                    if (TANH) v = tanhf(v);
                    if (CBF16) ((short*)Cv)[(size_t)(row + r) * ldc + col] = f2bf(v);
                    else       ((float*)Cv)[(size_t)(row + r) * ldc + col] = v;
                }
            }
        }
    }
}

// ---------------- one-pass attention, 4 b's per block ----------------
// 256 blocks x 512 threads (8 waves). Block handles b = 4*blockIdx + {0..3}.
// V held in registers per b; next b's V/P loads issued before the LDS
// reduce/store tail so the tail overlaps the next HBM stream.
#define NR 5
#define NCH 7
__global__ __launch_bounds__(512, 2) void attn_wc_multib(
        const float* __restrict__ V, const float* __restrict__ P,
        const int* __restrict__ tid, const float* __restrict__ kv,
        short* __restrict__ h, float* __restrict__ attn_out) {
    const int t = threadIdx.x;
    const int w = t >> 6, lane = t & 63;
    __shared__ float en[NV];
    __shared__ float ag[NV];
    __shared__ __align__(16) f32x4 part[8 * 448];   // 57 KB

    f32x4 p[NCH];
    f32x4 v[NR][NCH];

    auto issue_loads = [&](int b) {
        const f32x4* V4 = (const f32x4*)(V + (size_t)b * NV * CD);
        const f32x4* P4 = (const f32x4*)(P + (size_t)b * CD);
        #pragma unroll
        for (int j = 0; j < NCH; ++j) {
            int c = lane + 64 * j;
            p[j] = (c < CD4) ? P4[c] : (f32x4){0.f, 0.f, 0.f, 0.f};
        }
        #pragma unroll
        for (int r = 0; r < NR; ++r) {
            int n = w + 8 * r;
            #pragma unroll
            for (int j = 0; j < NCH; ++j) {
                int c = lane + 64 * j;
                v[r][j] = (n < NV && c < CD4) ? V4[(size_t)n * CD4 + c]
                                              : (f32x4){0.f, 0.f, 0.f, 0.f};
            }
        }
    };

    issue_loads(blockIdx.x * 4);

    for (int bi = 0; bi < 4; ++bi) {
        const int b = blockIdx.x * 4 + bi;

        // 1. energies: lane-local dot, wave reduce
        #pragma unroll
        for (int r = 0; r < NR; ++r) {
            float s = 0.f;
            #pragma unroll
            for (int j = 0; j < NCH; ++j) {
                f32x4 vv = v[r][j], pp = p[j];
                s += vv.x * pp.x + vv.y * pp.y + vv.z * pp.z + vv.w * pp.w;
            }
            #pragma unroll
            for (int off = 32; off > 0; off >>= 1) s += __shfl_xor(s, off);
            int n = w + 8 * r;
            if (lane == 0 && n < NV) en[n] = s;
        }
        __syncthreads();

        // 2. softmax + pano gating (wave 0)
        if (t < 64) {
            const float SCALE = 0.044194173824159216f;  // 512^-0.5
            float e = (t < NV) ? en[t] * SCALE : -1e30f;
            float m = e;
            #pragma unroll
            for (int off = 32; off > 0; off >>= 1) m = fmaxf(m, __shfl_xor(m, off));
            float pr = (t < NV) ? __expf(e - m) : 0.f;
            float s = pr;
            #pragma unroll
            for (int off = 32; off > 0; off >>= 1) s += __shfl_xor(s, off);
            float a = pr / s;
            if (t < NV) {
                attn_out[(size_t)b * NV + t] = a;
                ag[t] = a * pano_entry(tid[b], t);
            }
        }
        __syncthreads();

        // 3. weighted context from registers -> per-wave partials
        f32x4 acc[NCH];
        #pragma unroll
        for (int j = 0; j < NCH; ++j) acc[j] = (f32x4){0.f, 0.f, 0.f, 0.f};
        #pragma unroll
        for (int r = 0; r < NR; ++r) {
            int n = w + 8 * r;
            float a = (n < NV) ? ag[n] : 0.f;
            #pragma unroll
            for (int j = 0; j < NCH; ++j) {
                acc[j].x += a * v[r][j].x; acc[j].y += a * v[r][j].y;
                acc[j].z += a * v[r][j].z; acc[j].w += a * v[r][j].w;
            }
        }
        #pragma unroll
        for (int j = 0; j < NCH; ++j)
            part[w * 448 + lane + 64 * j] = acc[j];

        // v/p registers now dead: issue next b's HBM stream before the tail
        if (bi < 3) issue_loads(b + 1);
        __syncthreads();

        // 4. cross-wave reduce + bf16 store (overlaps next stream in flight)
        short* hb = h + (size_t)b * HLD;
        if (t < CD4) {
            f32x4 s = part[t];
            #pragma unroll
            for (int w2 = 1; w2 < 8; ++w2) {
                f32x4 q = part[w2 * 448 + t];
                s.x += q.x; s.y += q.y; s.z += q.z; s.w += q.w;
            }
            short4v o = { f2bf(s.x), f2bf(s.y), f2bf(s.z), f2bf(s.w) };
            *(short4v*)(hb + t * 4) = o;
        }
        if (t < KVD)
            hb[CD + QD + t] = f2bf(kv[(size_t)b * KVD + t]);
        // no barrier needed here: part[] next written after two barriers
    }
}

extern "C" void kernel_launch(void* const* d_in, const int* in_sizes, int n_in,
                              void* d_out, int out_size, void* d_ws, size_t ws_size,
                              hipStream_t stream) {
    const float* Q   = (const float*)d_in[0];
    const float* V   = (const float*)d_in[1];
    // d_in[2] = detect_feats: irrelevant (constant over views + softmax shift invariance)
    const float* kv  = (const float*)d_in[3];
    const int*   tid = (const int*)  d_in[4];
    const float* Wk  = (const float*)d_in[5];
    const float* Wq  = (const float*)d_in[6];
    const float* Wo  = (const float*)d_in[7];

    short* h    = (short*)d_ws;                     // (1024, 2200) bf16
    float* P    = (float*)(h + (size_t)BA * HLD);   // (1024, 1576) f32
    short* wq_b = (short*)(P + (size_t)BA * CD);    // (512, 512)  bf16
    short* wk_t = wq_b + (size_t)QD * QD;           // (1576, 512) bf16 (transposed)
    short* wo_b = wk_t + (size_t)CD * QD;           // (512, 2200) bf16

    float* out      = (float*)d_out;                // h_tilde (1024, 512)
    float* attn_out = out + (size_t)BA * QD;        // attn    (1024, 36)

    // 0) weights -> bf16 (+ Wk_v transpose)
    prep_weights<<<2156, 256, 0, stream>>>(Wk, Wq, Wo, wk_t, wq_b, wo_b);

    // 1) Qf = Q @ Wq^T (NT, A f32, C bf16) -> h[:, 1576:2088]
    gemm_nt<1, false, true, false><<<dim3(QD / 64, BA / 32), 256, 0, stream>>>(
        Q, wq_b, h + CD, BA, QD, QD, QD, QD, HLD);

    // 2) P = Qf @ Wk_v (NT vs transposed weights, A bf16, C f32)
    gemm_nt<2, true, false, false><<<dim3((CD + 63) / 64, BA / 64), 256, 0, stream>>>(
        h + CD, wk_t, P, BA, CD, QD, HLD, QD, CD);

    // 3) energy/softmax/pano/weighted-context + kv copy (V read once, 4 b/block)
    attn_wc_multib<<<BA / 4, 512, 0, stream>>>(V, P, tid, kv, h, attn_out);

    // 4) h_tilde = tanh(h @ Wo^T) (NT, A bf16, C f32)
    gemm_nt<1, true, false, true><<<dim3(QD / 64, BA / 32), 256, 0, stream>>>(
        h, wo_b, out, BA, QD, HLD, HLD, HLD, QD);
}